// Round 2
// baseline (204.860 us; speedup 1.0000x reference)
//
#include <hip/hip_runtime.h>
#include <math.h>

typedef __bf16 bf16_t;
typedef __bf16 bf16x8 __attribute__((ext_vector_type(8)));
typedef float f32x4 __attribute__((ext_vector_type(4)));

#define GLOAD_LDS16(g, l)                                                      \
  __builtin_amdgcn_global_load_lds(                                            \
      (const __attribute__((address_space(1))) void*)(g),                      \
      (__attribute__((address_space(3))) void*)(l), 16, 0, 0)

// ---------------------------------------------------------------------------
// Prep: build bf16 operands.
//  Acat  [1600][1024] = [enc | ot] rows (b*T+t)
//  Dec   [400][512]
//  WcatT [640][1024]  = concat(W_enc;W_ot) transposed  (row f, col k)
//  WdecT [640][512]   = W_dec transposed
//  WoutT [1024][640]  = W_out transposed               (row v, col f)
// ---------------------------------------------------------------------------
__global__ __launch_bounds__(256) void prep_kernel(
    const float* __restrict__ enc, const float* __restrict__ dec,
    const float* __restrict__ ot, const float* __restrict__ W_enc,
    const float* __restrict__ W_ot, const float* __restrict__ W_dec,
    const float* __restrict__ W_out, bf16_t* __restrict__ Acat,
    bf16_t* __restrict__ Dec, bf16_t* __restrict__ WcatT,
    bf16_t* __restrict__ WdecT, bf16_t* __restrict__ WoutT) {
  int idx = blockIdx.x * 256 + threadIdx.x;
  const int N0 = 1600 * 1024, N1 = 400 * 512, N2 = 640 * 1024, N3 = 640 * 512,
            N4 = 1024 * 640;
  if (idx < N0) {
    int r = idx >> 10, c = idx & 1023;
    float v = (c < 512) ? enc[(r << 9) + c] : ot[(r << 9) + (c - 512)];
    Acat[idx] = (bf16_t)v;
    return;
  }
  idx -= N0;
  if (idx < N1) {
    Dec[idx] = (bf16_t)dec[idx];
    return;
  }
  idx -= N1;
  if (idx < N2) {
    int f = idx >> 10, k = idx & 1023;
    float v = (k < 512) ? W_enc[k * 640 + f] : W_ot[(k - 512) * 640 + f];
    WcatT[idx] = (bf16_t)v;
    return;
  }
  idx -= N2;
  if (idx < N3) {
    int f = idx >> 9, k = idx & 511;
    WdecT[idx] = (bf16_t)W_dec[k * 640 + f];
    return;
  }
  idx -= N3;
  if (idx < N4) {
    int v = idx / 640, f = idx - v * 640;
    WoutT[idx] = (bf16_t)W_out[f * 1024 + v];
    return;
  }
}

// ---------------------------------------------------------------------------
// Stage 1: out[M][640] = tanh(A[M][K] @ Bt[640][K]^T + bias1 (+ bias2))
// 64x64 tile, 256 thr, 4 waves (2x2), each 32x32. BK=32.
// ---------------------------------------------------------------------------
__global__ __launch_bounds__(256) void gemm_tanh_kernel(
    const bf16_t* __restrict__ A, const bf16_t* __restrict__ Bt,
    const float* __restrict__ bias1, const float* __restrict__ bias2,
    float* __restrict__ out, int M, int K) {
  __shared__ bf16_t As[64 * 32];
  __shared__ bf16_t Bs[64 * 32];
  const int tid = threadIdx.x;
  const int wid = tid >> 6, lane = tid & 63;
  const int wm = wid >> 1, wn = wid & 1;
  const int r0 = blockIdx.y * 64, n0 = blockIdx.x * 64;

  // staging: wave wid stages 16-row (1 KB) chunk of A and of B
  const int ia = wid * 16 + (lane >> 2);
  const int sa = lane & 3;
  int ra = r0 + ia;
  if (ra > M - 1) ra = M - 1;
  const bf16_t* gA = A + (size_t)ra * K + sa * 8;
  const bf16_t* gB = Bt + (size_t)(n0 + ia) * K + sa * 8;
  bf16_t* lA = As + wid * 512;
  bf16_t* lB = Bs + wid * 512;

  f32x4 acc[2][2] = {};
  const int lr = lane & 15, kg = lane >> 4;
  const int steps = K >> 5;
  for (int ks = 0; ks < steps; ++ks) {
    GLOAD_LDS16(gA + ks * 32, lA);
    GLOAD_LDS16(gB + ks * 32, lB);
    __syncthreads();
    bf16x8 af[2], bfr[2];
#pragma unroll
    for (int a = 0; a < 2; ++a)
      af[a] = *(const bf16x8*)(As + (wm * 32 + a * 16 + lr) * 32 + kg * 8);
#pragma unroll
    for (int b = 0; b < 2; ++b)
      bfr[b] = *(const bf16x8*)(Bs + (wn * 32 + b * 16 + lr) * 32 + kg * 8);
#pragma unroll
    for (int a = 0; a < 2; ++a)
#pragma unroll
      for (int b = 0; b < 2; ++b)
        acc[a][b] =
            __builtin_amdgcn_mfma_f32_16x16x32_bf16(af[a], bfr[b], acc[a][b], 0, 0, 0);
    __syncthreads();
  }
#pragma unroll
  for (int a = 0; a < 2; ++a)
#pragma unroll
    for (int b = 0; b < 2; ++b) {
      int col = n0 + wn * 32 + b * 16 + lr;
      float bv = bias1[col] + (bias2 ? bias2[col] : 0.0f);
#pragma unroll
      for (int j = 0; j < 4; ++j) {
        int rg = r0 + wm * 32 + a * 16 + kg * 4 + j;
        if (rg < M) out[(size_t)rg * 640 + col] = tanhf(acc[a][b][j] + bv);
      }
    }
}

// ---------------------------------------------------------------------------
// Stage 2: fused joint GEMM.
//  out[80000][1024] = ( tanh-combined A[80000][640] ) @ WoutT^T + b_out
//  A row r = b*10000 + t*50 + u is computed on the fly:
//    joint = (ta[r/50] + tb[(r/10000)*50 + r%50]) / (1 + ta*tb)   (tanh identity)
//  Tile 128x256, 512 thr, 8 waves (2x4), each 64x64. BK=32, K=640 -> 20 steps.
// ---------------------------------------------------------------------------
__global__ __launch_bounds__(512) void joint_gemm_kernel(
    const float* __restrict__ ta,      // [1600][640]  tanh(fused)
    const float* __restrict__ tb,      // [400][640]   tanh(proj_dec)
    const bf16_t* __restrict__ WoutT,  // [1024][640]
    const float* __restrict__ b_out,   // [1024]
    float* __restrict__ out) {         // [80000][1024]
  __shared__ bf16_t As[128 * 32];
  __shared__ bf16_t Bs[256 * 32];
  const int tid = threadIdx.x;
  const int wid = tid >> 6, lane = tid & 63;
  const int wm = wid >> 2, wn = wid & 3;
  const int r0 = blockIdx.y * 128;
  const int n0 = blockIdx.x * 256;

  // ---- A staging assignment: thread -> (row i, 8-elem slot s) ----
  const int i = tid >> 2, s = tid & 3;
  const int r = r0 + i;
  const int frow = r / 50;
  const int bidx = r / 10000;
  const int u = r - frow * 50;
  const float* taP = ta + (size_t)frow * 640 + s * 8;
  const float* tbP = tb + (size_t)(bidx * 50 + u) * 640 + s * 8;
  bf16_t* aWp = As + i * 32 + s * 8;

  // ---- B staging: wave wid stages chunks 2*wid, 2*wid+1 (16 rows each) ----
  const int ib0 = wid * 32 + (lane >> 2);
  const int sb = lane & 3;
  const bf16_t* gB0 = WoutT + (size_t)(n0 + ib0) * 640 + sb * 8;
  const bf16_t* gB1 = gB0 + 16 * 640;
  bf16_t* lB0 = Bs + wid * 1024;
  bf16_t* lB1 = lB0 + 512;

  f32x4 acc[4][4] = {};
  const int lr = lane & 15, kg = lane >> 4;

  for (int ks = 0; ks < 20; ++ks) {
    const int k0 = ks * 32;
    // B tile: async global->LDS
    GLOAD_LDS16(gB0 + k0, lB0);
    GLOAD_LDS16(gB1 + k0, lB1);
    // A tile: compute tanh(a+b) via addition identity, pack bf16x8
    f32x4 xa0 = *(const f32x4*)(taP + k0);
    f32x4 xa1 = *(const f32x4*)(taP + k0 + 4);
    f32x4 xb0 = *(const f32x4*)(tbP + k0);
    f32x4 xb1 = *(const f32x4*)(tbP + k0 + 4);
    bf16x8 jv;
#pragma unroll
    for (int e = 0; e < 4; ++e) {
      float x = xa0[e], y = xb0[e];
      float d = fmaxf(1.0f + x * y, 1e-6f);
      jv[e] = (bf16_t)((x + y) * __builtin_amdgcn_rcpf(d));
      float x2 = xa1[e], y2 = xb1[e];
      float d2 = fmaxf(1.0f + x2 * y2, 1e-6f);
      jv[e + 4] = (bf16_t)((x2 + y2) * __builtin_amdgcn_rcpf(d2));
    }
    *(bf16x8*)aWp = jv;
    __syncthreads();

    bf16x8 af[4], bfr[4];
#pragma unroll
    for (int a = 0; a < 4; ++a)
      af[a] = *(const bf16x8*)(As + (wm * 64 + a * 16 + lr) * 32 + kg * 8);
#pragma unroll
    for (int b = 0; b < 4; ++b)
      bfr[b] = *(const bf16x8*)(Bs + (wn * 64 + b * 16 + lr) * 32 + kg * 8);
#pragma unroll
    for (int a = 0; a < 4; ++a)
#pragma unroll
      for (int b = 0; b < 4; ++b)
        acc[a][b] =
            __builtin_amdgcn_mfma_f32_16x16x32_bf16(af[a], bfr[b], acc[a][b], 0, 0, 0);
    __syncthreads();
  }

  // ---- epilogue: add b_out, store f32 ----
#pragma unroll
  for (int b = 0; b < 4; ++b) {
    const int col = n0 + wn * 64 + b * 16 + lr;
    const float bv = b_out[col];
#pragma unroll
    for (int a = 0; a < 4; ++a) {
      const int rg = r0 + wm * 64 + a * 16 + kg * 4;
      float* op = out + (size_t)rg * 1024 + col;
#pragma unroll
      for (int j = 0; j < 4; ++j) op[(size_t)j * 1024] = acc[a][b][j] + bv;
    }
  }
}

// ---------------------------------------------------------------------------
extern "C" void kernel_launch(void* const* d_in, const int* in_sizes, int n_in,
                              void* d_out, int out_size, void* d_ws,
                              size_t ws_size, hipStream_t stream) {
  const float* enc = (const float*)d_in[0];
  const float* dec = (const float*)d_in[1];
  const float* ot = (const float*)d_in[2];
  const float* W_enc = (const float*)d_in[3];
  const float* b_enc = (const float*)d_in[4];
  const float* W_ot = (const float*)d_in[5];
  const float* b_ot = (const float*)d_in[6];
  const float* W_dec = (const float*)d_in[7];
  const float* b_dec = (const float*)d_in[8];
  const float* W_out = (const float*)d_in[9];
  const float* b_out = (const float*)d_in[10];
  float* out = (float*)d_out;

  char* ws = (char*)d_ws;
  size_t off = 0;
  auto alloc = [&](size_t bytes) {
    void* p = ws + off;
    off += (bytes + 255) & ~(size_t)255;
    return p;
  };
  float* ta = (float*)alloc(1600 * 640 * 4);        // tanh(fused)
  float* tb = (float*)alloc(400 * 640 * 4);         // tanh(proj_dec)
  bf16_t* Acat = (bf16_t*)alloc(1600 * 1024 * 2);
  bf16_t* Dec = (bf16_t*)alloc(400 * 512 * 2);
  bf16_t* WcatT = (bf16_t*)alloc(640 * 1024 * 2);
  bf16_t* WdecT = (bf16_t*)alloc(640 * 512 * 2);
  bf16_t* WoutT = (bf16_t*)alloc(1024 * 640 * 2);

  prep_kernel<<<13600, 256, 0, stream>>>(enc, dec, ot, W_enc, W_ot, W_dec,
                                         W_out, Acat, Dec, WcatT, WdecT, WoutT);
  // fused = [enc|ot] @ Wcat + b_enc + b_ot  -> tanh -> ta
  gemm_tanh_kernel<<<dim3(10, 25), 256, 0, stream>>>(Acat, WcatT, b_enc, b_ot,
                                                     ta, 1600, 1024);
  // proj_dec = dec @ W_dec + b_dec -> tanh -> tb
  gemm_tanh_kernel<<<dim3(10, 7), 256, 0, stream>>>(Dec, WdecT, b_dec, nullptr,
                                                    tb, 400, 512);
  joint_gemm_kernel<<<dim3(4, 625), 512, 0, stream>>>(ta, tb, WoutT, b_out,
                                                      out);
}